// Round 1
// baseline (2097.164 us; speedup 1.0000x reference)
//
#include <hip/hip_runtime.h>
#include <math.h>

#define DD 128
#define HH 256

typedef __attribute__((ext_vector_type(8))) short bf16x8;
typedef __attribute__((ext_vector_type(4))) float f32x4;
typedef unsigned short u16;
typedef unsigned int u32;

__device__ __forceinline__ float bf2f(u16 u) {
  union { u32 i; float f; } v; v.i = ((u32)u) << 16; return v.f;
}
__device__ __forceinline__ u16 f2bf(float f) {
  union { u32 i; float f; } v; v.f = f;
  u32 r = v.i + 0x7FFFu + ((v.i >> 16) & 1u);
  return (u16)(r >> 16);
}

__global__ __launch_bounds__(256) void conv_f32_bf16(const float* __restrict__ in,
                                                     u16* __restrict__ out, int n) {
  int i = blockIdx.x * 256 + threadIdx.x;
  int stride = gridDim.x * 256;
  for (; i < n; i += stride) out[i] = f2bf(in[i]);
}

// tiny FCNN on the global feature vector (fp32, one block)
__global__ __launch_bounds__(256) void g3_kernel(const float* __restrict__ g,
    const float* __restrict__ W3a, const float* __restrict__ b3a,
    const float* __restrict__ W3b, const float* __restrict__ b3b,
    float* __restrict__ g3out) {
  __shared__ float gs[DD];
  __shared__ float hs[HH];
  int t = threadIdx.x;
  if (t < DD) gs[t] = g[t];
  __syncthreads();
  float acc = b3a[t];
  for (int k = 0; k < DD; ++k) acc = fmaf(gs[k], W3a[k * HH + t], acc);
  hs[t] = acc > 0.f ? acc : 0.f;
  __syncthreads();
  if (t < DD) {
    float o = b3b[t];
    for (int j = 0; j < HH; ++j) o = fmaf(hs[j], W3b[j * DD + t], o);
    g3out[t] = o;
  }
}

// C[M,N] = A[M,K] @ B[K,N] + bias (optional relu), bf16 in, bf16 out, fp32 accum.
// One wave computes 16x16 tiles; fixed n-tile per wave, grid-stride over m-tiles,
// B fragments preloaded once per wave (B is small and L2-resident).
template<int K, bool RELU>
__global__ __launch_bounds__(256) void gemm_bf16(const u16* __restrict__ A,
    const u16* __restrict__ B, const float* __restrict__ bias,
    u16* __restrict__ Dst, int M, int N) {
  const int wave = (blockIdx.x * 256 + threadIdx.x) >> 6;
  const int lane = threadIdx.x & 63;
  const int totalWaves = (gridDim.x * 256) >> 6;
  const int nTiles = N >> 4;
  const int wavesPerCol = totalWaves / nTiles;
  const int nt = wave % nTiles;
  const int mw = wave / nTiles;
  const int n0 = nt << 4;
  const int mTiles = (M + 15) >> 4;

  const int l15 = lane & 15;
  const int l4 = lane >> 4;  // 0..3
  constexpr int KB = K / 32;

  // preload B fragments: B[k = kb*32 + l4*8 + i][n0 + l15]
  bf16x8 bfrag[KB];
#pragma unroll
  for (int kb = 0; kb < KB; ++kb) {
#pragma unroll
    for (int i = 0; i < 8; ++i) {
      int k = kb * 32 + l4 * 8 + i;
      bfrag[kb][i] = (short)B[(size_t)k * N + n0 + l15];
    }
  }
  const float bcol = bias[n0 + l15];

  for (int mt = mw; mt < mTiles; mt += wavesPerCol) {
    const int m0 = mt << 4;
    int rowA = m0 + l15;
    if (rowA >= M) rowA = M - 1;
    const u16* arow = A + (size_t)rowA * K + l4 * 8;
    f32x4 acc = {0.f, 0.f, 0.f, 0.f};
#pragma unroll
    for (int kb = 0; kb < KB; ++kb) {
      bf16x8 afrag = *(const bf16x8*)(arow + kb * 32);
      acc = __builtin_amdgcn_mfma_f32_16x16x32_bf16(afrag, bfrag[kb], acc, 0, 0, 0);
    }
#pragma unroll
    for (int r = 0; r < 4; ++r) {
      int row = m0 + l4 * 4 + r;
      if (row < M) {
        float v = acc[r] + bcol;
        if (RELU) v = v > 0.f ? v : 0.f;
        Dst[(size_t)row * N + n0 + l15] = f2bf(v);
      }
    }
  }
}

// one wave per edge: sigmoid + 4 scatter-adds (denom x2, agg x2)
__global__ __launch_bounds__(256) void edge_kernel(const float* __restrict__ ef,
    const int* __restrict__ src, const int* __restrict__ dst,
    const u16* __restrict__ h2, float* __restrict__ denom,
    float* __restrict__ agg, int E) {
  const int wid = (blockIdx.x * 256 + threadIdx.x) >> 6;
  if (wid >= E) return;
  const int lane = threadIdx.x & 63;
  const int a = src[wid];
  const int b = dst[wid];
  const int d0 = lane * 2;

  float2 e2 = *(const float2*)(ef + (size_t)wid * DD + d0);
  float sx = 1.f / (1.f + __expf(-e2.x));
  float sy = 1.f / (1.f + __expf(-e2.y));

  u32 hb = *(const u32*)(h2 + (size_t)b * DD + d0);
  u32 ha = *(const u32*)(h2 + (size_t)a * DD + d0);
  float hbx = bf2f((u16)(hb & 0xffffu)), hby = bf2f((u16)(hb >> 16));
  float hax = bf2f((u16)(ha & 0xffffu)), hay = bf2f((u16)(ha >> 16));

  float* dena = denom + (size_t)a * DD + d0;
  float* denb = denom + (size_t)b * DD + d0;
  float* agga = agg + (size_t)a * DD + d0;
  float* aggb = agg + (size_t)b * DD + d0;
  unsafeAtomicAdd(dena, sx);
  unsafeAtomicAdd(dena + 1, sy);
  unsafeAtomicAdd(denb, sx);
  unsafeAtomicAdd(denb + 1, sy);
  unsafeAtomicAdd(agga, sx * hbx);
  unsafeAtomicAdd(agga + 1, sy * hby);
  unsafeAtomicAdd(aggb, sx * hax);
  unsafeAtomicAdd(aggb + 1, sy * hay);
}

// one wave per node row: inter = h1 + agg/denom + g3; InstanceNorm over D; out = x + relu(norm)
__global__ __launch_bounds__(256) void final_kernel(const float* __restrict__ x,
    const u16* __restrict__ h1, const float* __restrict__ agg,
    const float* __restrict__ denom, const float* __restrict__ g3,
    float* __restrict__ out, int N) {
  const int row = (blockIdx.x * 256 + threadIdx.x) >> 6;
  if (row >= N) return;
  const int lane = threadIdx.x & 63;
  const int d0 = lane * 2;
  const size_t base = (size_t)row * DD + d0;

  float2 xv = *(const float2*)(x + base);
  u32 h1u = *(const u32*)(h1 + base);
  float2 ag = *(const float2*)(agg + base);
  float2 dn = *(const float2*)(denom + base);
  float2 gv = *(const float2*)(g3 + d0);

  float i0 = bf2f((u16)(h1u & 0xffffu)) + ag.x / (dn.x + 1e-7f) + gv.x;
  float i1 = bf2f((u16)(h1u >> 16)) + ag.y / (dn.y + 1e-7f) + gv.y;

  float s = i0 + i1;
  float q = i0 * i0 + i1 * i1;
#pragma unroll
  for (int off = 32; off; off >>= 1) {
    s += __shfl_xor(s, off);
    q += __shfl_xor(q, off);
  }
  float mean = s * (1.f / 128.f);
  float var = q * (1.f / 128.f) - mean * mean;
  float rstd = rsqrtf(var + 1e-5f);
  float n0v = (i0 - mean) * rstd;
  float n1v = (i1 - mean) * rstd;
  float o0 = xv.x + (n0v > 0.f ? n0v : 0.f);
  float o1 = xv.y + (n1v > 0.f ? n1v : 0.f);
  *(float2*)(out + base) = make_float2(o0, o1);
}

extern "C" void kernel_launch(void* const* d_in, const int* in_sizes, int n_in,
                              void* d_out, int out_size, void* d_ws, size_t ws_size,
                              hipStream_t stream) {
  const float* x   = (const float*)d_in[0];
  const int*   eix = (const int*)d_in[1];
  const float* ef  = (const float*)d_in[2];
  const float* gf  = (const float*)d_in[3];
  const float* W1a = (const float*)d_in[4];
  const float* b1a = (const float*)d_in[5];
  const float* W1b = (const float*)d_in[6];
  const float* b1b = (const float*)d_in[7];
  const float* W2a = (const float*)d_in[8];
  const float* b2a = (const float*)d_in[9];
  const float* W2b = (const float*)d_in[10];
  const float* b2b = (const float*)d_in[11];
  const float* W3a = (const float*)d_in[12];
  const float* b3a = (const float*)d_in[13];
  const float* W3b = (const float*)d_in[14];
  const float* b3b = (const float*)d_in[15];

  const int N = in_sizes[0] / DD;
  const int E = in_sizes[2] / DD;
  const int* srcI = eix;
  const int* dstI = eix + E;

  char* p = (char*)d_ws;
  auto take = [&](size_t bytes) -> char* {
    char* r = p;
    p += (bytes + 255) & ~(size_t)255;
    return r;
  };
  u16* xb    = (u16*)take((size_t)N * DD * 2);
  u16* w1ab  = (u16*)take((size_t)DD * HH * 2);
  u16* w1bb  = (u16*)take((size_t)DD * HH * 2);
  u16* w2ab  = (u16*)take((size_t)DD * HH * 2);
  u16* w2bb  = (u16*)take((size_t)DD * HH * 2);
  u16* hidb  = (u16*)take((size_t)N * HH * 2);
  u16* h1b   = (u16*)take((size_t)N * DD * 2);
  u16* h2b   = (u16*)take((size_t)N * DD * 2);
  float* den = (float*)take((size_t)N * DD * 4);
  float* agg = (float*)take((size_t)N * DD * 4);
  float* g3  = (float*)take((size_t)DD * 4);

  hipMemsetAsync(den, 0, (size_t)N * DD * 4, stream);
  hipMemsetAsync(agg, 0, (size_t)N * DD * 4, stream);

  conv_f32_bf16<<<4096, 256, 0, stream>>>(x, xb, N * DD);
  conv_f32_bf16<<<64, 256, 0, stream>>>(W1a, w1ab, DD * HH);
  conv_f32_bf16<<<64, 256, 0, stream>>>(W1b, w1bb, DD * HH);
  conv_f32_bf16<<<64, 256, 0, stream>>>(W2a, w2ab, DD * HH);
  conv_f32_bf16<<<64, 256, 0, stream>>>(W2b, w2bb, DD * HH);
  g3_kernel<<<1, 256, 0, stream>>>(gf, W3a, b3a, W3b, b3b, g3);

  // FCNN1: h1 = relu(x@W1a+b1a)@W1b + b1b
  gemm_bf16<128, true ><<<1024, 256, 0, stream>>>(xb,   w1ab, b1a, hidb, N, HH);
  gemm_bf16<256, false><<<1024, 256, 0, stream>>>(hidb, w1bb, b1b, h1b,  N, DD);
  // FCNN2: h2 = relu(x@W2a+b2a)@W2b + b2b
  gemm_bf16<128, true ><<<1024, 256, 0, stream>>>(xb,   w2ab, b2a, hidb, N, HH);
  gemm_bf16<256, false><<<1024, 256, 0, stream>>>(hidb, w2bb, b2b, h2b,  N, DD);

  edge_kernel<<<(E + 3) / 4, 256, 0, stream>>>(ef, srcI, dstI, h2b, den, agg, E);
  final_kernel<<<(N + 3) / 4, 256, 0, stream>>>(x, h1b, agg, den, g3, (float*)d_out, N);
}

// Round 2
// 569.896 us; speedup vs baseline: 3.6799x; 3.6799x over previous
//
#include <hip/hip_runtime.h>
#include <math.h>

#define DD 128
#define HH 256

typedef __attribute__((ext_vector_type(8))) short bf16x8;
typedef __attribute__((ext_vector_type(4))) float f32x4;
typedef unsigned short u16;
typedef unsigned int u32;

__device__ __forceinline__ float bf2f(u16 u) {
  union { u32 i; float f; } v; v.i = ((u32)u) << 16; return v.f;
}
__device__ __forceinline__ u16 f2bf(float f) {
  union { u32 i; float f; } v; v.f = f;
  u32 r = v.i + 0x7FFFu + ((v.i >> 16) & 1u);
  return (u16)(r >> 16);
}

__global__ __launch_bounds__(256) void conv_f32_bf16(const float* __restrict__ in,
                                                     u16* __restrict__ out, int n) {
  int i = blockIdx.x * 256 + threadIdx.x;
  int stride = gridDim.x * 256;
  for (; i < n; i += stride) out[i] = f2bf(in[i]);
}

// tiny FCNN on the global feature vector (fp32, one block)
__global__ __launch_bounds__(256) void g3_kernel(const float* __restrict__ g,
    const float* __restrict__ W3a, const float* __restrict__ b3a,
    const float* __restrict__ W3b, const float* __restrict__ b3b,
    float* __restrict__ g3out) {
  __shared__ float gs[DD];
  __shared__ float hs[HH];
  int t = threadIdx.x;
  if (t < DD) gs[t] = g[t];
  __syncthreads();
  float acc = b3a[t];
  for (int k = 0; k < DD; ++k) acc = fmaf(gs[k], W3a[k * HH + t], acc);
  hs[t] = acc > 0.f ? acc : 0.f;
  __syncthreads();
  if (t < DD) {
    float o = b3b[t];
    for (int j = 0; j < HH; ++j) o = fmaf(hs[j], W3b[j * DD + t], o);
    g3out[t] = o;
  }
}

// C[M,N] = A[M,K] @ B[K,N] + bias (optional relu), bf16 in, bf16 out, fp32 accum.
template<int K, bool RELU>
__global__ __launch_bounds__(256) void gemm_bf16(const u16* __restrict__ A,
    const u16* __restrict__ B, const float* __restrict__ bias,
    u16* __restrict__ Dst, int M, int N) {
  const int wave = (blockIdx.x * 256 + threadIdx.x) >> 6;
  const int lane = threadIdx.x & 63;
  const int totalWaves = (gridDim.x * 256) >> 6;
  const int nTiles = N >> 4;
  const int wavesPerCol = totalWaves / nTiles;
  const int nt = wave % nTiles;
  const int mw = wave / nTiles;
  const int n0 = nt << 4;
  const int mTiles = (M + 15) >> 4;

  const int l15 = lane & 15;
  const int l4 = lane >> 4;  // 0..3
  constexpr int KB = K / 32;

  bf16x8 bfrag[KB];
#pragma unroll
  for (int kb = 0; kb < KB; ++kb) {
#pragma unroll
    for (int i = 0; i < 8; ++i) {
      int k = kb * 32 + l4 * 8 + i;
      bfrag[kb][i] = (short)B[(size_t)k * N + n0 + l15];
    }
  }
  const float bcol = bias[n0 + l15];

  for (int mt = mw; mt < mTiles; mt += wavesPerCol) {
    const int m0 = mt << 4;
    int rowA = m0 + l15;
    if (rowA >= M) rowA = M - 1;
    const u16* arow = A + (size_t)rowA * K + l4 * 8;
    f32x4 acc = {0.f, 0.f, 0.f, 0.f};
#pragma unroll
    for (int kb = 0; kb < KB; ++kb) {
      bf16x8 afrag = *(const bf16x8*)(arow + kb * 32);
      acc = __builtin_amdgcn_mfma_f32_16x16x32_bf16(afrag, bfrag[kb], acc, 0, 0, 0);
    }
#pragma unroll
    for (int r = 0; r < 4; ++r) {
      int row = m0 + l4 * 4 + r;
      if (row < M) {
        float v = acc[r] + bcol;
        if (RELU) v = v > 0.f ? v : 0.f;
        Dst[(size_t)row * N + n0 + l15] = f2bf(v);
      }
    }
  }
}

// ---- CSR build ----
// entries t in [0, 2E): t<E -> src side of edge t; t>=E -> dst side of edge t-E
__global__ __launch_bounds__(256) void count_kernel(const int* __restrict__ eix,
                                                    u32* __restrict__ deg, int twoE) {
  int t = blockIdx.x * 256 + threadIdx.x;
  int stride = gridDim.x * 256;
  for (; t < twoE; t += stride) atomicAdd(&deg[eix[t]], 1u);
}

__global__ __launch_bounds__(1024) void scan_kernel(const u32* __restrict__ deg,
    u32* __restrict__ rowstart, u32* __restrict__ cursor, int N) {
  __shared__ u32 part[1024];
  const int t = threadIdx.x;
  const int chunk = (N + 1023) >> 10;
  const int b = t * chunk;
  const int e = min(b + chunk, N);
  u32 s = 0;
  for (int i = b; i < e; ++i) s += deg[i];
  part[t] = s;
  __syncthreads();
  for (int off = 1; off < 1024; off <<= 1) {
    u32 v = (t >= off) ? part[t - off] : 0u;
    __syncthreads();
    part[t] += v;
    __syncthreads();
  }
  u32 run = (t == 0) ? 0u : part[t - 1];
  for (int i = b; i < e; ++i) {
    rowstart[i] = run;
    cursor[i] = run;
    run += deg[i];
  }
  if (t == 1023) rowstart[N] = part[1023];
}

__global__ __launch_bounds__(256) void scatter_kernel(const int* __restrict__ eix,
    u32* __restrict__ cursor, uint2* __restrict__ adj, int E) {
  int t = blockIdx.x * 256 + threadIdx.x;
  int stride = gridDim.x * 256;
  int twoE = 2 * E;
  for (; t < twoE; t += stride) {
    int node, eid, other;
    if (t < E) { node = eix[t];     eid = t;     other = eix[t + E]; }
    else       { node = eix[t];     eid = t - E; other = eix[t - E]; }
    u32 pos = atomicAdd(&cursor[node], 1u);
    adj[pos] = make_uint2((u32)eid, (u32)other);
  }
}

// ---- fused gather + instance-norm + residual ----
// one wave per node, lane handles 2 features
__global__ __launch_bounds__(256) void gather_final(const float* __restrict__ x,
    const u16* __restrict__ h1, const u16* __restrict__ h2,
    const float* __restrict__ ef, const uint2* __restrict__ adj,
    const u32* __restrict__ rowstart, const float* __restrict__ g3,
    float* __restrict__ out, int N) {
  int row = (blockIdx.x * 256 + threadIdx.x) >> 6;
  if (row >= N) return;
  row = __builtin_amdgcn_readfirstlane(row);
  const int lane = threadIdx.x & 63;
  const int d0 = lane * 2;

  const u32 beg = rowstart[row];
  const u32 end = rowstart[row + 1];

  float dx = 0.f, dy = 0.f, ax = 0.f, ay = 0.f;
  for (u32 j = beg; j < end; ++j) {
    uint2 en = adj[j];  // wave-uniform
    float2 e2 = *(const float2*)(ef + (size_t)en.x * DD + d0);
    u32 hu = *(const u32*)(h2 + (size_t)en.y * DD + d0);
    float sx = 1.f / (1.f + __expf(-e2.x));
    float sy = 1.f / (1.f + __expf(-e2.y));
    float hx = bf2f((u16)(hu & 0xffffu));
    float hy = bf2f((u16)(hu >> 16));
    dx += sx; dy += sy;
    ax = fmaf(sx, hx, ax);
    ay = fmaf(sy, hy, ay);
  }

  const size_t base = (size_t)row * DD + d0;
  float2 xv = *(const float2*)(x + base);
  u32 h1u = *(const u32*)(h1 + base);
  float2 gv = *(const float2*)(g3 + d0);

  float i0 = bf2f((u16)(h1u & 0xffffu)) + ax / (dx + 1e-7f) + gv.x;
  float i1 = bf2f((u16)(h1u >> 16)) + ay / (dy + 1e-7f) + gv.y;

  float s = i0 + i1;
  float q = i0 * i0 + i1 * i1;
#pragma unroll
  for (int off = 32; off; off >>= 1) {
    s += __shfl_xor(s, off);
    q += __shfl_xor(q, off);
  }
  float mean = s * (1.f / 128.f);
  float var = q * (1.f / 128.f) - mean * mean;
  float rstd = rsqrtf(var + 1e-5f);
  float n0v = (i0 - mean) * rstd;
  float n1v = (i1 - mean) * rstd;
  float o0 = xv.x + (n0v > 0.f ? n0v : 0.f);
  float o1 = xv.y + (n1v > 0.f ? n1v : 0.f);
  *(float2*)(out + base) = make_float2(o0, o1);
}

extern "C" void kernel_launch(void* const* d_in, const int* in_sizes, int n_in,
                              void* d_out, int out_size, void* d_ws, size_t ws_size,
                              hipStream_t stream) {
  const float* x   = (const float*)d_in[0];
  const int*   eix = (const int*)d_in[1];
  const float* ef  = (const float*)d_in[2];
  const float* gf  = (const float*)d_in[3];
  const float* W1a = (const float*)d_in[4];
  const float* b1a = (const float*)d_in[5];
  const float* W1b = (const float*)d_in[6];
  const float* b1b = (const float*)d_in[7];
  const float* W2a = (const float*)d_in[8];
  const float* b2a = (const float*)d_in[9];
  const float* W2b = (const float*)d_in[10];
  const float* b2b = (const float*)d_in[11];
  const float* W3a = (const float*)d_in[12];
  const float* b3a = (const float*)d_in[13];
  const float* W3b = (const float*)d_in[14];
  const float* b3b = (const float*)d_in[15];

  const int N = in_sizes[0] / DD;
  const int E = in_sizes[2] / DD;

  char* p = (char*)d_ws;
  auto take = [&](size_t bytes) -> char* {
    char* r = p;
    p += (bytes + 255) & ~(size_t)255;
    return r;
  };
  u16* xb    = (u16*)take((size_t)N * DD * 2);
  u16* w1ab  = (u16*)take((size_t)DD * HH * 2);
  u16* w1bb  = (u16*)take((size_t)DD * HH * 2);
  u16* w2ab  = (u16*)take((size_t)DD * HH * 2);
  u16* w2bb  = (u16*)take((size_t)DD * HH * 2);
  u16* hidb  = (u16*)take((size_t)N * HH * 2);
  u16* h1b   = (u16*)take((size_t)N * DD * 2);
  u16* h2b   = (u16*)take((size_t)N * DD * 2);
  u32* deg   = (u32*)take((size_t)N * 4);
  u32* rowst = (u32*)take((size_t)(N + 1) * 4);
  u32* curs  = (u32*)take((size_t)N * 4);
  uint2* adj = (uint2*)take((size_t)2 * E * 8);
  float* g3  = (float*)take((size_t)DD * 4);

  hipMemsetAsync(deg, 0, (size_t)N * 4, stream);

  conv_f32_bf16<<<4096, 256, 0, stream>>>(x, xb, N * DD);
  conv_f32_bf16<<<64, 256, 0, stream>>>(W1a, w1ab, DD * HH);
  conv_f32_bf16<<<64, 256, 0, stream>>>(W1b, w1bb, DD * HH);
  conv_f32_bf16<<<64, 256, 0, stream>>>(W2a, w2ab, DD * HH);
  conv_f32_bf16<<<64, 256, 0, stream>>>(W2b, w2bb, DD * HH);
  g3_kernel<<<1, 256, 0, stream>>>(gf, W3a, b3a, W3b, b3b, g3);

  // CSR build (only depends on eix)
  count_kernel<<<2048, 256, 0, stream>>>(eix, deg, 2 * E);
  scan_kernel<<<1, 1024, 0, stream>>>(deg, rowst, curs, N);
  scatter_kernel<<<2048, 256, 0, stream>>>(eix, curs, adj, E);

  // FCNN1: h1 = relu(x@W1a+b1a)@W1b + b1b
  gemm_bf16<128, true ><<<1024, 256, 0, stream>>>(xb,   w1ab, b1a, hidb, N, HH);
  gemm_bf16<256, false><<<1024, 256, 0, stream>>>(hidb, w1bb, b1b, h1b,  N, DD);
  // FCNN2: h2 = relu(x@W2a+b2a)@W2b + b2b
  gemm_bf16<128, true ><<<1024, 256, 0, stream>>>(xb,   w2ab, b2a, hidb, N, HH);
  gemm_bf16<256, false><<<1024, 256, 0, stream>>>(hidb, w2bb, b2b, h2b,  N, DD);

  gather_final<<<(N + 3) / 4, 256, 0, stream>>>(x, h1b, h2b, ef, adj, rowst, g3,
                                                (float*)d_out, N);
}